// Round 1
// baseline (690.799 us; speedup 1.0000x reference)
//
#include <hip/hip_runtime.h>
#include <hip/hip_bf16.h>

typedef __attribute__((ext_vector_type(8))) short short8_t;
typedef __attribute__((ext_vector_type(4))) float f32x4;

#define NNODES 50000
#define FIN 1433
#define HID 128
#define NCLS 7
#define KPAD 1440   // FIN padded to multiple of 32

static __device__ __forceinline__ unsigned short f2bf(float f) {
    union { float f; unsigned int u; } v; v.f = f;
    unsigned int u = v.u;
    u += 0x7FFFu + ((u >> 16) & 1u);   // round-to-nearest-even
    return (unsigned short)(u >> 16);
}
static __device__ __forceinline__ float bf2f(unsigned short b) {
    union { unsigned int u; float f; } v; v.u = ((unsigned int)b) << 16; return v.f;
}

// ---------------- degree / norm ----------------
__global__ void init_deg(int* deg, int n) {
    int i = blockIdx.x * blockDim.x + threadIdx.x;
    if (i < n) deg[i] = 1;              // self loop
}

__global__ void count_deg(const int* __restrict__ dst, int E, int* deg, int n) {
    int e = blockIdx.x * blockDim.x + threadIdx.x;
    if (e < E) {
        int d = dst[e];
        if ((unsigned)d < (unsigned)n) atomicAdd(&deg[d], 1);
    }
}

__global__ void calc_dinv(const int* __restrict__ deg, float* dinv, int n) {
    int i = blockIdx.x * blockDim.x + threadIdx.x;
    if (i < n) dinv[i] = rsqrtf((float)deg[i]);
}

// ---------------- CSR build ----------------
// single block, 1024 threads; chunked exclusive scan of (deg-1)
__global__ void scan_deg(const int* __restrict__ deg, int* ptr, int* cursor, int n) {
    __shared__ int sums[1024];
    int t = threadIdx.x;
    const int CH = (n + 1023) / 1024;
    int start = t * CH, end = min(start + CH, n);
    int s = 0;
    for (int i = start; i < end; ++i) s += deg[i] - 1;
    sums[t] = s;
    __syncthreads();
    for (int off = 1; off < 1024; off <<= 1) {
        int v = (t >= off) ? sums[t - off] : 0;
        __syncthreads();
        sums[t] += v;
        __syncthreads();
    }
    int base = (t == 0) ? 0 : sums[t - 1];
    for (int i = start; i < end; ++i) {
        ptr[i] = base; cursor[i] = base;
        base += deg[i] - 1;
    }
}

__global__ void fill_csr(const int* __restrict__ src, const int* __restrict__ dst,
                         int E, int* cursor, int* csr, int n) {
    int e = blockIdx.x * blockDim.x + threadIdx.x;
    if (e < E) {
        int d = dst[e], s = src[e];
        if ((unsigned)d < (unsigned)n && (unsigned)s < (unsigned)n) {
            int pos = atomicAdd(&cursor[d], 1);
            csr[pos] = s;
        }
    }
}

// ---------------- W1 transpose+cast:  W1[FIN][HID] f32 -> W1t[HID][KPAD] bf16 ----------------
__global__ void transpose_w1(const float* __restrict__ W1, unsigned short* __restrict__ W1t) {
    int id = blockIdx.x * 256 + threadIdx.x;
    if (id >= HID * KPAD) return;
    int nn = id / KPAD, k = id % KPAD;
    float v = (k < FIN) ? W1[k * HID + nn] : 0.f;
    W1t[id] = f2bf(v);
}

// ---------------- GEMM1: h[M][128] (bf16) = x[M][1433] @ W1 ----------------
// BM=64, BK=32, 256 threads (4 waves as 2x2 over 64rows x 128cols)
__global__ __launch_bounds__(256) void gemm1(const float* __restrict__ x,
                                             const unsigned short* __restrict__ W1t,
                                             unsigned short* __restrict__ h, int M) {
    __shared__ unsigned short As[2048];  // [unit 4][row 64][8]
    __shared__ unsigned short Bs[4096];  // [unit 4][col 128][8]
    int t = threadIdx.x;
    int wave = t >> 6, lane = t & 63;
    int wm = wave >> 1, wn = wave & 1;
    int r = lane & 15, u = lane >> 4;
    long rowBase = (long)blockIdx.x * 64;
    f32x4 acc[2][4] = {};

    const int KT = (FIN + 31) / 32;   // 45
    for (int kk = 0; kk < KT; ++kk) {
        int k0 = kk * 32;
        __syncthreads();
        // stage A: 64x32, 8 elems/thread, coalesced along k
        #pragma unroll
        for (int i = 0; i < 8; ++i) {
            int idx = i * 256 + t;
            int row = idx >> 5, k = idx & 31;
            long gr = rowBase + row;
            int gk = k0 + k;
            float v = (gr < M && gk < FIN) ? x[gr * (long)FIN + gk] : 0.f;
            As[(k >> 3) * 512 + row * 8 + (k & 7)] = f2bf(v);
        }
        // stage B: 128x32 bf16 (as 2048 uints), 8 uints/thread
        #pragma unroll
        for (int i = 0; i < 8; ++i) {
            int idx = i * 256 + t;
            int nn = idx >> 4, kp = idx & 15, k = kp * 2;
            unsigned int v = *(const unsigned int*)(W1t + nn * KPAD + k0 + k);
            *(unsigned int*)(&Bs[(k >> 3) * 1024 + nn * 8 + (k & 7)]) = v;
        }
        __syncthreads();
        short8_t af[2], bfr[4];
        #pragma unroll
        for (int mi = 0; mi < 2; ++mi)
            af[mi] = *(const short8_t*)(As + u * 512 + (wm * 32 + mi * 16 + r) * 8);
        #pragma unroll
        for (int ni = 0; ni < 4; ++ni)
            bfr[ni] = *(const short8_t*)(Bs + u * 1024 + (wn * 64 + ni * 16 + r) * 8);
        #pragma unroll
        for (int mi = 0; mi < 2; ++mi)
            #pragma unroll
            for (int ni = 0; ni < 4; ++ni)
                acc[mi][ni] = __builtin_amdgcn_mfma_f32_16x16x32_bf16(af[mi], bfr[ni], acc[mi][ni], 0, 0, 0);
    }
    // epilogue: C layout col=lane&15, row=(lane>>4)*4+reg
    #pragma unroll
    for (int mi = 0; mi < 2; ++mi) {
        #pragma unroll
        for (int reg = 0; reg < 4; ++reg) {
            long grow = rowBase + wm * 32 + mi * 16 + u * 4 + reg;
            if (grow < M) {
                #pragma unroll
                for (int ni = 0; ni < 4; ++ni) {
                    int gcol = wn * 64 + ni * 16 + r;
                    h[grow * HID + gcol] = f2bf(acc[mi][ni][reg]);
                }
            }
        }
    }
}

// ---------------- Aggregation 1 + bias + relu + @W2 fused ----------------
// one wave per node; lane holds features {2l, 2l+1}
__global__ __launch_bounds__(256) void agg1(const unsigned short* __restrict__ h,
                                            const int* __restrict__ ptr,
                                            const int* __restrict__ deg,
                                            const int* __restrict__ csr,
                                            const float* __restrict__ dinv,
                                            const float* __restrict__ b1,
                                            const float* __restrict__ W2,
                                            float* __restrict__ h2s, int n) {
    __shared__ float W2s[HID * NCLS];
    for (int i = threadIdx.x; i < HID * NCLS; i += 256) W2s[i] = W2[i];
    __syncthreads();
    int wave = threadIdx.x >> 6, lane = threadIdx.x & 63;
    int v = blockIdx.x * 4 + wave;
    if (v >= n) return;
    float dv = dinv[v];
    int p0 = ptr[v], cnt = deg[v] - 1;
    float a0 = 0.f, a1 = 0.f;
    // self loop
    {
        unsigned int hv = *(const unsigned int*)(h + (long)v * HID + lane * 2);
        float nrm = dv * dv;
        a0 += nrm * bf2f((unsigned short)(hv & 0xffffu));
        a1 += nrm * bf2f((unsigned short)(hv >> 16));
    }
    for (int j = 0; j < cnt; ++j) {
        int s = csr[p0 + j];
        float nrm = dv * dinv[s];
        unsigned int hv = *(const unsigned int*)(h + (long)s * HID + lane * 2);
        a0 += nrm * bf2f((unsigned short)(hv & 0xffffu));
        a1 += nrm * bf2f((unsigned short)(hv >> 16));
    }
    int f0 = lane * 2, f1 = lane * 2 + 1;
    float v0 = fmaxf(a0 + b1[f0], 0.f);
    float v1 = fmaxf(a1 + b1[f1], 0.f);
    float p[NCLS];
    #pragma unroll
    for (int c = 0; c < NCLS; ++c)
        p[c] = v0 * W2s[f0 * NCLS + c] + v1 * W2s[f1 * NCLS + c];
    #pragma unroll
    for (int off = 32; off >= 1; off >>= 1)
        #pragma unroll
        for (int c = 0; c < NCLS; ++c)
            p[c] += __shfl_xor(p[c], off, 64);
    if (lane == 0) {
        #pragma unroll
        for (int c = 0; c < NCLS; ++c) h2s[(long)v * 8 + c] = p[c];
        h2s[(long)v * 8 + 7] = 0.f;
    }
}

// ---------------- Aggregation 2 + bias ----------------
// 8 lanes per node (lane c = feature c, c==7 dummy)
__global__ __launch_bounds__(256) void agg2(const float* __restrict__ h2s,
                                            const int* __restrict__ ptr,
                                            const int* __restrict__ deg,
                                            const int* __restrict__ csr,
                                            const float* __restrict__ dinv,
                                            const float* __restrict__ b2,
                                            float* __restrict__ out, int n) {
    int g = threadIdx.x >> 3, c = threadIdx.x & 7;
    int v = blockIdx.x * 32 + g;
    if (v >= n) return;
    float dv = dinv[v];
    int p0 = ptr[v], cnt = deg[v] - 1;
    float acc = dv * dv * h2s[(long)v * 8 + c];
    for (int j = 0; j < cnt; ++j) {
        int s = csr[p0 + j];
        acc += dv * dinv[s] * h2s[(long)s * 8 + c];
    }
    if (c < NCLS) out[(long)v * NCLS + c] = acc + b2[c];
}

extern "C" void kernel_launch(void* const* d_in, const int* in_sizes, int n_in,
                              void* d_out, int out_size, void* d_ws, size_t ws_size,
                              hipStream_t stream) {
    const float* x  = (const float*)d_in[0];
    const int*   ei = (const int*)d_in[1];    // int64 in reference but JAX default x64-off => int32
    const float* W1 = (const float*)d_in[2];
    const float* b1 = (const float*)d_in[3];
    const float* W2 = (const float*)d_in[4];
    const float* b2 = (const float*)d_in[5];
    float* out = (float*)d_out;

    const int N = NNODES;
    const int E = in_sizes[1] / 2;
    const int* src = ei;
    const int* dst = ei + E;

    char* ws = (char*)d_ws;
    size_t off = 0;
    auto alloc = [&](size_t bytes) {
        void* p = ws + off;
        off += (bytes + 255) & ~(size_t)255;
        return p;
    };
    int*   deg    = (int*)alloc((size_t)N * 4);
    float* dinv   = (float*)alloc((size_t)N * 4);
    int*   ptr    = (int*)alloc((size_t)N * 4);
    int*   cursor = (int*)alloc((size_t)N * 4);
    int*   csr    = (int*)alloc((size_t)E * 4);
    unsigned short* W1t = (unsigned short*)alloc((size_t)HID * KPAD * 2);
    unsigned short* h   = (unsigned short*)alloc((size_t)N * HID * 2);
    float* h2s    = (float*)alloc((size_t)N * 8 * 4);

    init_deg<<<(N + 255) / 256, 256, 0, stream>>>(deg, N);
    count_deg<<<(E + 255) / 256, 256, 0, stream>>>(dst, E, deg, N);
    calc_dinv<<<(N + 255) / 256, 256, 0, stream>>>(deg, dinv, N);
    scan_deg<<<1, 1024, 0, stream>>>(deg, ptr, cursor, N);
    fill_csr<<<(E + 255) / 256, 256, 0, stream>>>(src, dst, E, cursor, csr, N);
    transpose_w1<<<(HID * KPAD + 255) / 256, 256, 0, stream>>>(W1, W1t);
    gemm1<<<(N + 63) / 64, 256, 0, stream>>>(x, W1t, h, N);
    agg1<<<(N + 3) / 4, 256, 0, stream>>>(h, ptr, deg, csr, dinv, b1, W2, h2s, N);
    agg2<<<(N + 31) / 32, 256, 0, stream>>>(h2s, ptr, deg, csr, dinv, b2, out, N);
}

// Round 2
// 631.773 us; speedup vs baseline: 1.0934x; 1.0934x over previous
//
#include <hip/hip_runtime.h>
#include <hip/hip_bf16.h>

typedef __attribute__((ext_vector_type(8))) short short8_t;
typedef __attribute__((ext_vector_type(4))) float f32x4;
typedef float f32x4u __attribute__((ext_vector_type(4), aligned(4)));  // 4B-aligned vector load

#define NNODES 50000
#define FIN 1433
#define HID 128
#define NCLS 7
#define KT1 23          // ceil(1433/64)
#define BK 64

static __device__ __forceinline__ unsigned short f2bf(float f) {
    union { float f; unsigned int u; } v; v.f = f;
    unsigned int u = v.u;
    u += 0x7FFFu + ((u >> 16) & 1u);   // round-to-nearest-even
    return (unsigned short)(u >> 16);
}
static __device__ __forceinline__ float bf2f(unsigned short b) {
    union { unsigned int u; float f; } v; v.u = ((unsigned int)b) << 16; return v.f;
}

// ---------------- degree / norm ----------------
__global__ void init_deg(int* deg, int n) {
    int i = blockIdx.x * blockDim.x + threadIdx.x;
    if (i < n) deg[i] = 1;              // self loop
}

__global__ void count_deg(const int* __restrict__ dst, int E, int* deg, int n) {
    int e = blockIdx.x * blockDim.x + threadIdx.x;
    if (e < E) {
        int d = dst[e];
        if ((unsigned)d < (unsigned)n) atomicAdd(&deg[d], 1);
    }
}

__global__ void calc_dinv(const int* __restrict__ deg, float* dinv, int n) {
    int i = blockIdx.x * blockDim.x + threadIdx.x;
    if (i < n) dinv[i] = rsqrtf((float)deg[i]);
}

// ---------------- CSR build ----------------
__global__ void scan_deg(const int* __restrict__ deg, int* ptr, int* cursor, int n) {
    __shared__ int sums[1024];
    int t = threadIdx.x;
    const int CH = (n + 1023) / 1024;
    int start = t * CH, end = min(start + CH, n);
    int s = 0;
    for (int i = start; i < end; ++i) s += deg[i] - 1;
    sums[t] = s;
    __syncthreads();
    for (int off = 1; off < 1024; off <<= 1) {
        int v = (t >= off) ? sums[t - off] : 0;
        __syncthreads();
        sums[t] += v;
        __syncthreads();
    }
    int base = (t == 0) ? 0 : sums[t - 1];
    for (int i = start; i < end; ++i) {
        ptr[i] = base; cursor[i] = base;
        base += deg[i] - 1;
    }
}

__global__ void fill_csr(const int* __restrict__ src, const int* __restrict__ dst,
                         int E, int* cursor, int* csr, int n) {
    int e = blockIdx.x * blockDim.x + threadIdx.x;
    if (e < E) {
        int d = dst[e], s = src[e];
        if ((unsigned)d < (unsigned)n && (unsigned)s < (unsigned)n) {
            int pos = atomicAdd(&cursor[d], 1);
            csr[pos] = s;
        }
    }
}

// ---------------- W1 pack: W1[FIN][HID] f32 -> W1s[KT1][1024 segs][8 bf16]
// seg = g*128 + c  (g = k-octet within BK tile, c = output col); LDS-tile order.
__global__ void prep_w1(const float* __restrict__ W1, unsigned short* __restrict__ W1s) {
    int tid = blockIdx.x * 256 + threadIdx.x;
    if (tid >= KT1 * 1024) return;
    int kt = tid >> 10, seg = tid & 1023;
    int c = seg & 127, g = seg >> 7;
    int kb = kt * BK + g * 8;
    unsigned int w[4];
    #pragma unroll
    for (int p = 0; p < 4; ++p) {
        int k0 = kb + p * 2, k1 = kb + p * 2 + 1;
        unsigned short lo = (k0 < FIN) ? f2bf(W1[(size_t)k0 * HID + c]) : (unsigned short)0;
        unsigned short hi = (k1 < FIN) ? f2bf(W1[(size_t)k1 * HID + c]) : (unsigned short)0;
        w[p] = (unsigned int)lo | ((unsigned int)hi << 16);
    }
    uint4* dstp = (uint4*)(W1s + (size_t)tid * 8);
    uint4 val; val.x = w[0]; val.y = w[1]; val.z = w[2]; val.w = w[3];
    *dstp = val;
}

// ---------------- GEMM1: h[M][128] (bf16) = x[M][1433] @ W1 ----------------
// BM=64, BK=64, 256 threads (4 waves 2x2 over 64 rows x 128 cols), double-buffered.
__global__ __launch_bounds__(256) void gemm1(const float* __restrict__ x,
                                             const unsigned short* __restrict__ W1s,
                                             unsigned short* __restrict__ h, int M) {
    // A: [row 64][ (g*8) ^ ((row&7)<<3) .. +7 ]  (XOR-swizzled, 8KB/buf)
    // B: [g 8][c 128][8]  (linear, matches global_load_lds order, 16KB/buf)
    __shared__ unsigned short As[2][4096];
    __shared__ unsigned short Bs[2][8192];
    const int t = threadIdx.x;
    const int wave = t >> 6, lane = t & 63;
    const int wm = wave >> 1, wn = wave & 1;
    const int r = lane & 15, u = lane >> 4;
    const long rowBase = (long)blockIdx.x * 64;
    f32x4 acc[2][4] = {};

    float4 areg[4];

    auto issueA = [&](int kt) {
        int k0 = kt * BK;
        #pragma unroll
        for (int i = 0; i < 4; ++i) {
            int idx = i * 256 + t;
            int row = idx >> 4, kq = idx & 15;
            long gr = rowBase + row;
            int gk = k0 + kq * 4;
            if (gr < M && gk + 3 < FIN) {
                f32x4u v = *(const f32x4u*)(x + gr * (long)FIN + gk);
                areg[i].x = v.x; areg[i].y = v.y; areg[i].z = v.z; areg[i].w = v.w;
            } else {
                areg[i].x = (gr < M && gk + 0 < FIN) ? x[gr * (long)FIN + gk + 0] : 0.f;
                areg[i].y = (gr < M && gk + 1 < FIN) ? x[gr * (long)FIN + gk + 1] : 0.f;
                areg[i].z = (gr < M && gk + 2 < FIN) ? x[gr * (long)FIN + gk + 2] : 0.f;
                areg[i].w = (gr < M && gk + 3 < FIN) ? x[gr * (long)FIN + gk + 3] : 0.f;
            }
        }
    };
    auto issueB = [&](int kt, int buf) {
        #pragma unroll
        for (int i = 0; i < 4; ++i) {
            // per-lane global src; wave-uniform LDS base (lane*16 auto-added by HW)
            const unsigned short* gp = W1s + ((size_t)kt * 1024 + (size_t)(i * 256 + t)) * 8;
            unsigned short* lp = &Bs[buf][(i * 256 + wave * 64) * 8];
            __builtin_amdgcn_global_load_lds(
                (const __attribute__((address_space(1))) unsigned int*)gp,
                (__attribute__((address_space(3))) unsigned int*)lp, 16, 0, 0);
        }
    };
    auto writeA = [&](int buf) {
        #pragma unroll
        for (int i = 0; i < 4; ++i) {
            int idx = i * 256 + t;
            int row = idx >> 4, kq = idx & 15;
            unsigned int lo = (unsigned int)f2bf(areg[i].x) | ((unsigned int)f2bf(areg[i].y) << 16);
            unsigned int hi = (unsigned int)f2bf(areg[i].z) | ((unsigned int)f2bf(areg[i].w) << 16);
            unsigned long long pk = ((unsigned long long)hi << 32) | (unsigned long long)lo;
            int us = row * 64 + ((kq * 4) ^ ((row & 7) << 3));
            *(unsigned long long*)(&As[buf][us]) = pk;
        }
    };
    auto compute = [&](int buf) {
        short8_t af[2][2], bfr[2][4];
        #pragma unroll
        for (int ks = 0; ks < 2; ++ks) {
            int g = ks * 4 + u;
            #pragma unroll
            for (int mi = 0; mi < 2; ++mi) {
                int row = wm * 32 + mi * 16 + r;
                int us = row * 64 + ((g * 8) ^ ((row & 7) << 3));
                af[ks][mi] = *(const short8_t*)(&As[buf][us]);
            }
            #pragma unroll
            for (int ni = 0; ni < 4; ++ni) {
                int c = wn * 64 + ni * 16 + r;
                bfr[ks][ni] = *(const short8_t*)(&Bs[buf][g * 1024 + c * 8]);
            }
        }
        #pragma unroll
        for (int ks = 0; ks < 2; ++ks)
            #pragma unroll
            for (int mi = 0; mi < 2; ++mi)
                #pragma unroll
                for (int ni = 0; ni < 4; ++ni)
                    acc[mi][ni] = __builtin_amdgcn_mfma_f32_16x16x32_bf16(af[ks][mi], bfr[ks][ni], acc[mi][ni], 0, 0, 0);
    };

    // prologue
    issueB(0, 0);
    issueA(0);
    writeA(0);                 // compiler waits A-load vmcnt before use
    __syncthreads();           // drains gload_lds (vmcnt 0) + A writes visible

    int cur = 0;
    for (int kt = 0; kt < KT1; ++kt) {
        int nxt = cur ^ 1;
        if (kt + 1 < KT1) { issueB(kt + 1, nxt); issueA(kt + 1); }
        compute(cur);
        if (kt + 1 < KT1) {
            __syncthreads();   // all reads of cur done; stage loads landed
            writeA(nxt);
            __syncthreads();   // A[nxt] visible
        }
        cur = nxt;
    }

    // epilogue: C layout col=lane&15, row=(lane>>4)*4+reg
    #pragma unroll
    for (int mi = 0; mi < 2; ++mi) {
        #pragma unroll
        for (int reg = 0; reg < 4; ++reg) {
            long grow = rowBase + wm * 32 + mi * 16 + u * 4 + reg;
            if (grow < M) {
                #pragma unroll
                for (int ni = 0; ni < 4; ++ni) {
                    int gcol = wn * 64 + ni * 16 + r;
                    h[grow * HID + gcol] = f2bf(acc[mi][ni][reg]);
                }
            }
        }
    }
}

// ---------------- Aggregation 1 + bias + relu + @W2 fused ----------------
__global__ __launch_bounds__(256) void agg1(const unsigned short* __restrict__ h,
                                            const int* __restrict__ ptr,
                                            const int* __restrict__ deg,
                                            const int* __restrict__ csr,
                                            const float* __restrict__ dinv,
                                            const float* __restrict__ b1,
                                            const float* __restrict__ W2,
                                            float* __restrict__ h2s, int n) {
    __shared__ float W2s[HID * NCLS];
    for (int i = threadIdx.x; i < HID * NCLS; i += 256) W2s[i] = W2[i];
    __syncthreads();
    int wave = threadIdx.x >> 6, lane = threadIdx.x & 63;
    int v = blockIdx.x * 4 + wave;
    if (v >= n) return;
    float dv = dinv[v];
    int p0 = ptr[v], cnt = deg[v] - 1;
    float a0 = 0.f, a1 = 0.f;
    {
        unsigned int hv = *(const unsigned int*)(h + (long)v * HID + lane * 2);
        float nrm = dv * dv;
        a0 += nrm * bf2f((unsigned short)(hv & 0xffffu));
        a1 += nrm * bf2f((unsigned short)(hv >> 16));
    }
    for (int j = 0; j < cnt; ++j) {
        int s = csr[p0 + j];
        float nrm = dv * dinv[s];
        unsigned int hv = *(const unsigned int*)(h + (long)s * HID + lane * 2);
        a0 += nrm * bf2f((unsigned short)(hv & 0xffffu));
        a1 += nrm * bf2f((unsigned short)(hv >> 16));
    }
    int f0 = lane * 2, f1 = lane * 2 + 1;
    float v0 = fmaxf(a0 + b1[f0], 0.f);
    float v1 = fmaxf(a1 + b1[f1], 0.f);
    float p[NCLS];
    #pragma unroll
    for (int c = 0; c < NCLS; ++c)
        p[c] = v0 * W2s[f0 * NCLS + c] + v1 * W2s[f1 * NCLS + c];
    #pragma unroll
    for (int off = 32; off >= 1; off >>= 1)
        #pragma unroll
        for (int c = 0; c < NCLS; ++c)
            p[c] += __shfl_xor(p[c], off, 64);
    if (lane == 0) {
        #pragma unroll
        for (int c = 0; c < NCLS; ++c) h2s[(long)v * 8 + c] = p[c];
        h2s[(long)v * 8 + 7] = 0.f;
    }
}

// ---------------- Aggregation 2 + bias ----------------
__global__ __launch_bounds__(256) void agg2(const float* __restrict__ h2s,
                                            const int* __restrict__ ptr,
                                            const int* __restrict__ deg,
                                            const int* __restrict__ csr,
                                            const float* __restrict__ dinv,
                                            const float* __restrict__ b2,
                                            float* __restrict__ out, int n) {
    int g = threadIdx.x >> 3, c = threadIdx.x & 7;
    int v = blockIdx.x * 32 + g;
    if (v >= n) return;
    float dv = dinv[v];
    int p0 = ptr[v], cnt = deg[v] - 1;
    float acc = dv * dv * h2s[(long)v * 8 + c];
    for (int j = 0; j < cnt; ++j) {
        int s = csr[p0 + j];
        acc += dv * dinv[s] * h2s[(long)s * 8 + c];
    }
    if (c < NCLS) out[(long)v * NCLS + c] = acc + b2[c];
}

extern "C" void kernel_launch(void* const* d_in, const int* in_sizes, int n_in,
                              void* d_out, int out_size, void* d_ws, size_t ws_size,
                              hipStream_t stream) {
    const float* x  = (const float*)d_in[0];
    const int*   ei = (const int*)d_in[1];    // int64 in reference but JAX x64-off => int32
    const float* W1 = (const float*)d_in[2];
    const float* b1 = (const float*)d_in[3];
    const float* W2 = (const float*)d_in[4];
    const float* b2 = (const float*)d_in[5];
    float* out = (float*)d_out;

    const int N = NNODES;
    const int E = in_sizes[1] / 2;
    const int* src = ei;
    const int* dst = ei + E;

    char* ws = (char*)d_ws;
    size_t off = 0;
    auto alloc = [&](size_t bytes) {
        void* p = ws + off;
        off += (bytes + 255) & ~(size_t)255;
        return p;
    };
    int*   deg    = (int*)alloc((size_t)N * 4);
    float* dinv   = (float*)alloc((size_t)N * 4);
    int*   ptr    = (int*)alloc((size_t)N * 4);
    int*   cursor = (int*)alloc((size_t)N * 4);
    int*   csr    = (int*)alloc((size_t)E * 4);
    unsigned short* W1s = (unsigned short*)alloc((size_t)KT1 * 1024 * 8 * 2);
    unsigned short* h   = (unsigned short*)alloc((size_t)N * HID * 2);
    float* h2s    = (float*)alloc((size_t)N * 8 * 4);

    init_deg<<<(N + 255) / 256, 256, 0, stream>>>(deg, N);
    count_deg<<<(E + 255) / 256, 256, 0, stream>>>(dst, E, deg, N);
    calc_dinv<<<(N + 255) / 256, 256, 0, stream>>>(deg, dinv, N);
    scan_deg<<<1, 1024, 0, stream>>>(deg, ptr, cursor, N);
    fill_csr<<<(E + 255) / 256, 256, 0, stream>>>(src, dst, E, cursor, csr, N);
    prep_w1<<<(KT1 * 1024 + 255) / 256, 256, 0, stream>>>(W1, W1s);
    gemm1<<<(N + 63) / 64, 256, 0, stream>>>(x, W1s, h, N);
    agg1<<<(N + 3) / 4, 256, 0, stream>>>(h, ptr, deg, csr, dinv, b1, W2, h2s, N);
    agg2<<<(N + 31) / 32, 256, 0, stream>>>(h2s, ptr, deg, csr, dinv, b2, out, N);
}

// Round 3
// 577.981 us; speedup vs baseline: 1.1952x; 1.0931x over previous
//
#include <hip/hip_runtime.h>
#include <hip/hip_bf16.h>

typedef __attribute__((ext_vector_type(8))) short short8_t;
typedef __attribute__((ext_vector_type(4))) float f32x4;
typedef float f32x4u __attribute__((ext_vector_type(4), aligned(4)));  // 4B-aligned vector load

#define NNODES 50000
#define FIN 1433
#define HID 128
#define NCLS 7
#define KT1 23          // ceil(1433/64)
#define BK 64
#define BM 96

static __device__ __forceinline__ unsigned short f2bf(float f) {
    union { float f; unsigned int u; } v; v.f = f;
    unsigned int u = v.u;
    u += 0x7FFFu + ((u >> 16) & 1u);   // round-to-nearest-even
    return (unsigned short)(u >> 16);
}
static __device__ __forceinline__ float bf2f(unsigned short b) {
    union { unsigned int u; float f; } v; v.u = ((unsigned int)b) << 16; return v.f;
}
static __device__ __forceinline__ unsigned short cvt1(float f) {
    __hip_bfloat16 h = __float2bfloat16(f);
    return *reinterpret_cast<unsigned short*>(&h);
}

// ---------------- degree / norm ----------------
__global__ void init_deg(int* deg, int n) {
    int i = blockIdx.x * blockDim.x + threadIdx.x;
    if (i < n) deg[i] = 1;              // self loop
}

__global__ void count_deg(const int* __restrict__ dst, int E, int* deg, int n) {
    int e = blockIdx.x * blockDim.x + threadIdx.x;
    if (e < E) {
        int d = dst[e];
        if ((unsigned)d < (unsigned)n) atomicAdd(&deg[d], 1);
    }
}

__global__ void calc_dinv(const int* __restrict__ deg, float* dinv, int n) {
    int i = blockIdx.x * blockDim.x + threadIdx.x;
    if (i < n) dinv[i] = rsqrtf((float)deg[i]);
}

// ---------------- CSR build ----------------
__global__ void scan_deg(const int* __restrict__ deg, int* ptr, int* cursor, int n) {
    __shared__ int sums[1024];
    int t = threadIdx.x;
    const int CH = (n + 1023) / 1024;
    int start = t * CH, end = min(start + CH, n);
    int s = 0;
    for (int i = start; i < end; ++i) s += deg[i] - 1;
    sums[t] = s;
    __syncthreads();
    for (int off = 1; off < 1024; off <<= 1) {
        int v = (t >= off) ? sums[t - off] : 0;
        __syncthreads();
        sums[t] += v;
        __syncthreads();
    }
    int base = (t == 0) ? 0 : sums[t - 1];
    for (int i = start; i < end; ++i) {
        ptr[i] = base; cursor[i] = base;
        base += deg[i] - 1;
    }
}

__global__ void fill_csr(const int* __restrict__ src, const int* __restrict__ dst,
                         int E, int* cursor, int* csr, int n) {
    int e = blockIdx.x * blockDim.x + threadIdx.x;
    if (e < E) {
        int d = dst[e], s = src[e];
        if ((unsigned)d < (unsigned)n && (unsigned)s < (unsigned)n) {
            int pos = atomicAdd(&cursor[d], 1);
            csr[pos] = s;
        }
    }
}

// ---------------- W1 pack: W1[FIN][HID] f32 -> W1s[KT1][1024 segs][8 bf16]
// seg = g*128 + c  (g = k-octet within BK tile, c = output col)
__global__ void prep_w1(const float* __restrict__ W1, unsigned short* __restrict__ W1s) {
    int tid = blockIdx.x * 256 + threadIdx.x;
    if (tid >= KT1 * 1024) return;
    int kt = tid >> 10, seg = tid & 1023;
    int c = seg & 127, g = seg >> 7;
    int kb = kt * BK + g * 8;
    unsigned int w[4];
    #pragma unroll
    for (int p = 0; p < 4; ++p) {
        int k0 = kb + p * 2, k1 = kb + p * 2 + 1;
        unsigned short lo = (k0 < FIN) ? f2bf(W1[(size_t)k0 * HID + c]) : (unsigned short)0;
        unsigned short hi = (k1 < FIN) ? f2bf(W1[(size_t)k1 * HID + c]) : (unsigned short)0;
        w[p] = (unsigned int)lo | ((unsigned int)hi << 16);
    }
    uint4* dstp = (uint4*)(W1s + (size_t)tid * 8);
    uint4 val; val.x = w[0]; val.y = w[1]; val.z = w[2]; val.w = w[3];
    *dstp = val;
}

// ---------------- GEMM1: h[M][128] (bf16) = x[M][1433] @ W1 ----------------
// BM=96, 256 threads (4 waves 2x2 over 96 rows x 128 cols). No LDS, no barriers:
// A direct from x (f32 -> cvt_pk bf16 in reg), B direct from packed W1s (L2-hot).
__global__ __launch_bounds__(256, 3) void gemm1(const float* __restrict__ x,
                                                const unsigned short* __restrict__ W1s,
                                                unsigned short* __restrict__ h, int M) {
    const int t = threadIdx.x;
    const int wave = t >> 6, lane = t & 63;
    const int wm = wave >> 1, wn = wave & 1;
    const int r = lane & 15, u = lane >> 4;
    const int rowBase = blockIdx.x * BM;
    f32x4 acc[3][4] = {};

    // clamped row bases (OOB rows read row 0: garbage only feeds unstored C rows)
    int rowOff[3];
    #pragma unroll
    for (int mi = 0; mi < 3; ++mi) {
        int row = rowBase + wm * 48 + mi * 16 + r;
        rowOff[mi] = (row < M ? row : 0) * FIN;
    }

    auto cvt8 = [&](f32x4u a, f32x4u b) -> short8_t {
        short8_t o;
        o[0] = (short)cvt1(a.x); o[1] = (short)cvt1(a.y);
        o[2] = (short)cvt1(a.z); o[3] = (short)cvt1(a.w);
        o[4] = (short)cvt1(b.x); o[5] = (short)cvt1(b.y);
        o[6] = (short)cvt1(b.z); o[7] = (short)cvt1(b.w);
        return o;
    };

    // B lane-base in ushorts: seg = (g*128 + wn*64 + ni*16 + r), elem = seg*8
    const int blane = (u * 128 + wn * 64 + r) * 8;

    #pragma unroll 2
    for (int kt = 0; kt < KT1 - 1; ++kt) {
        short8_t af[2][3], bfr[2][4];
        #pragma unroll
        for (int ks = 0; ks < 2; ++ks) {
            const int kof = kt * BK + (ks * 4 + u) * 8;
            #pragma unroll
            for (int mi = 0; mi < 3; ++mi) {
                const float* p = x + rowOff[mi] + kof;
                f32x4u v0 = *(const f32x4u*)p;
                f32x4u v1 = *(const f32x4u*)(p + 4);
                af[ks][mi] = cvt8(v0, v1);
            }
            #pragma unroll
            for (int ni = 0; ni < 4; ++ni)
                bfr[ks][ni] = *(const short8_t*)(W1s + (size_t)kt * 8192 + ks * 4096 + ni * 128 + blane);
        }
        #pragma unroll
        for (int ks = 0; ks < 2; ++ks)
            #pragma unroll
            for (int mi = 0; mi < 3; ++mi)
                #pragma unroll
                for (int ni = 0; ni < 4; ++ni)
                    acc[mi][ni] = __builtin_amdgcn_mfma_f32_16x16x32_bf16(af[ks][mi], bfr[ks][ni], acc[mi][ni], 0, 0, 0);
    }

    // K-tail: kt = 22, k = 1408..1432 (ks=0 only; ks=1 octets are all >= FIN)
    {
        const int kt = KT1 - 1;
        short8_t af[3], bfr[4];
        const int kof = kt * BK + u * 8;           // 1408 + u*8
        #pragma unroll
        for (int mi = 0; mi < 3; ++mi) {
            if (u < 3) {
                const float* p = x + rowOff[mi] + kof;
                f32x4u v0 = *(const f32x4u*)p;
                f32x4u v1 = *(const f32x4u*)(p + 4);
                af[mi] = cvt8(v0, v1);
            } else {
                short8_t o = {};
                o[0] = (short)cvt1(x[rowOff[mi] + FIN - 1]);  // k=1432
                af[mi] = o;
            }
        }
        #pragma unroll
        for (int ni = 0; ni < 4; ++ni)
            bfr[ni] = *(const short8_t*)(W1s + (size_t)kt * 8192 + ni * 128 + blane);
        #pragma unroll
        for (int mi = 0; mi < 3; ++mi)
            #pragma unroll
            for (int ni = 0; ni < 4; ++ni)
                acc[mi][ni] = __builtin_amdgcn_mfma_f32_16x16x32_bf16(af[mi], bfr[ni], acc[mi][ni], 0, 0, 0);
    }

    // epilogue: C layout col=lane&15, row=(lane>>4)*4+reg
    #pragma unroll
    for (int mi = 0; mi < 3; ++mi) {
        #pragma unroll
        for (int reg = 0; reg < 4; ++reg) {
            int grow = rowBase + wm * 48 + mi * 16 + u * 4 + reg;
            if (grow < M) {
                #pragma unroll
                for (int ni = 0; ni < 4; ++ni) {
                    int gcol = wn * 64 + ni * 16 + r;
                    h[(size_t)grow * HID + gcol] = f2bf(acc[mi][ni][reg]);
                }
            }
        }
    }
}

// ---------------- Aggregation 1 + bias + relu + @W2 fused ----------------
__global__ __launch_bounds__(256) void agg1(const unsigned short* __restrict__ h,
                                            const int* __restrict__ ptr,
                                            const int* __restrict__ deg,
                                            const int* __restrict__ csr,
                                            const float* __restrict__ dinv,
                                            const float* __restrict__ b1,
                                            const float* __restrict__ W2,
                                            float* __restrict__ h2s, int n) {
    __shared__ float W2s[HID * NCLS];
    for (int i = threadIdx.x; i < HID * NCLS; i += 256) W2s[i] = W2[i];
    __syncthreads();
    int wave = threadIdx.x >> 6, lane = threadIdx.x & 63;
    int v = blockIdx.x * 4 + wave;
    if (v >= n) return;
    float dv = dinv[v];
    int p0 = ptr[v], cnt = deg[v] - 1;
    float a0 = 0.f, a1 = 0.f;
    {
        unsigned int hv = *(const unsigned int*)(h + (size_t)v * HID + lane * 2);
        float nrm = dv * dv;
        a0 += nrm * bf2f((unsigned short)(hv & 0xffffu));
        a1 += nrm * bf2f((unsigned short)(hv >> 16));
    }
    #pragma unroll 4
    for (int j = 0; j < cnt; ++j) {
        int s = csr[p0 + j];
        float nrm = dv * dinv[s];
        unsigned int hv = *(const unsigned int*)(h + (size_t)s * HID + lane * 2);
        a0 += nrm * bf2f((unsigned short)(hv & 0xffffu));
        a1 += nrm * bf2f((unsigned short)(hv >> 16));
    }
    int f0 = lane * 2, f1 = lane * 2 + 1;
    float v0 = fmaxf(a0 + b1[f0], 0.f);
    float v1 = fmaxf(a1 + b1[f1], 0.f);
    float p[NCLS];
    #pragma unroll
    for (int c = 0; c < NCLS; ++c)
        p[c] = v0 * W2s[f0 * NCLS + c] + v1 * W2s[f1 * NCLS + c];
    #pragma unroll
    for (int off = 32; off >= 1; off >>= 1)
        #pragma unroll
        for (int c = 0; c < NCLS; ++c)
            p[c] += __shfl_xor(p[c], off, 64);
    if (lane == 0) {
        #pragma unroll
        for (int c = 0; c < NCLS; ++c) h2s[(size_t)v * 8 + c] = p[c];
        h2s[(size_t)v * 8 + 7] = 0.f;
    }
}

// ---------------- Aggregation 2 + bias ----------------
__global__ __launch_bounds__(256) void agg2(const float* __restrict__ h2s,
                                            const int* __restrict__ ptr,
                                            const int* __restrict__ deg,
                                            const int* __restrict__ csr,
                                            const float* __restrict__ dinv,
                                            const float* __restrict__ b2,
                                            float* __restrict__ out, int n) {
    int g = threadIdx.x >> 3, c = threadIdx.x & 7;
    int v = blockIdx.x * 32 + g;
    if (v >= n) return;
    float dv = dinv[v];
    int p0 = ptr[v], cnt = deg[v] - 1;
    float acc = dv * dv * h2s[(size_t)v * 8 + c];
    #pragma unroll 4
    for (int j = 0; j < cnt; ++j) {
        int s = csr[p0 + j];
        acc += dv * dinv[s] * h2s[(size_t)s * 8 + c];
    }
    if (c < NCLS) out[(size_t)v * NCLS + c] = acc + b2[c];
}

extern "C" void kernel_launch(void* const* d_in, const int* in_sizes, int n_in,
                              void* d_out, int out_size, void* d_ws, size_t ws_size,
                              hipStream_t stream) {
    const float* x  = (const float*)d_in[0];
    const int*   ei = (const int*)d_in[1];    // int64 in reference but JAX x64-off => int32
    const float* W1 = (const float*)d_in[2];
    const float* b1 = (const float*)d_in[3];
    const float* W2 = (const float*)d_in[4];
    const float* b2 = (const float*)d_in[5];
    float* out = (float*)d_out;

    const int N = NNODES;
    const int E = in_sizes[1] / 2;
    const int* src = ei;
    const int* dst = ei + E;

    char* ws = (char*)d_ws;
    size_t off = 0;
    auto alloc = [&](size_t bytes) {
        void* p = ws + off;
        off += (bytes + 255) & ~(size_t)255;
        return p;
    };
    int*   deg    = (int*)alloc((size_t)N * 4);
    float* dinv   = (float*)alloc((size_t)N * 4);
    int*   ptr    = (int*)alloc((size_t)N * 4);
    int*   cursor = (int*)alloc((size_t)N * 4);
    int*   csr    = (int*)alloc((size_t)E * 4);
    unsigned short* W1s = (unsigned short*)alloc((size_t)KT1 * 1024 * 8 * 2);
    unsigned short* h   = (unsigned short*)alloc((size_t)N * HID * 2);
    float* h2s    = (float*)alloc((size_t)N * 8 * 4);

    init_deg<<<(N + 255) / 256, 256, 0, stream>>>(deg, N);
    count_deg<<<(E + 255) / 256, 256, 0, stream>>>(dst, E, deg, N);
    calc_dinv<<<(N + 255) / 256, 256, 0, stream>>>(deg, dinv, N);
    scan_deg<<<1, 1024, 0, stream>>>(deg, ptr, cursor, N);
    fill_csr<<<(E + 255) / 256, 256, 0, stream>>>(src, dst, E, cursor, csr, N);
    prep_w1<<<(KT1 * 1024 + 255) / 256, 256, 0, stream>>>(W1, W1s);
    gemm1<<<(N + BM - 1) / BM, 256, 0, stream>>>(x, W1s, h, N);
    agg1<<<(N + 3) / 4, 256, 0, stream>>>(h, ptr, deg, csr, dinv, b1, W2, h2s, N);
    agg2<<<(N + 31) / 32, 256, 0, stream>>>(h2s, ptr, deg, csr, dinv, b2, out, N);
}

// Round 4
// 494.209 us; speedup vs baseline: 1.3978x; 1.1695x over previous
//
#include <hip/hip_runtime.h>
#include <hip/hip_bf16.h>

typedef __attribute__((ext_vector_type(8))) short short8_t;
typedef __attribute__((ext_vector_type(4))) float f32x4;
typedef float f32x4u __attribute__((ext_vector_type(4), aligned(4)));  // 4B-aligned vector load

#define NNODES 50000
#define FIN 1433
#define HID 128
#define NCLS 7
#define KT1 23          // ceil(1433/64)
#define BK 64
#define BM 128

static __device__ __forceinline__ unsigned short f2bf(float f) {
    union { float f; unsigned int u; } v; v.f = f;
    unsigned int u = v.u;
    u += 0x7FFFu + ((u >> 16) & 1u);   // round-to-nearest-even
    return (unsigned short)(u >> 16);
}
static __device__ __forceinline__ float bf2f(unsigned short b) {
    union { unsigned int u; float f; } v; v.u = ((unsigned int)b) << 16; return v.f;
}

// ---------------- degree / norm ----------------
__global__ void init_deg(int* deg, int n) {
    int i = blockIdx.x * blockDim.x + threadIdx.x;
    if (i < n) deg[i] = 1;              // self loop
}

__global__ void count_deg(const int* __restrict__ dst, int E, int* deg, int n) {
    int e = blockIdx.x * blockDim.x + threadIdx.x;
    if (e < E) {
        int d = dst[e];
        if ((unsigned)d < (unsigned)n) atomicAdd(&deg[d], 1);
    }
}

__global__ void calc_dinv(const int* __restrict__ deg, float* dinv, int n) {
    int i = blockIdx.x * blockDim.x + threadIdx.x;
    if (i < n) dinv[i] = rsqrtf((float)deg[i]);
}

// ---------------- CSR build ----------------
__global__ void scan_deg(const int* __restrict__ deg, int* ptr, int* cursor, int n) {
    __shared__ int sums[1024];
    int t = threadIdx.x;
    const int CH = (n + 1023) / 1024;
    int start = t * CH, end = min(start + CH, n);
    int s = 0;
    for (int i = start; i < end; ++i) s += deg[i] - 1;
    sums[t] = s;
    __syncthreads();
    for (int off = 1; off < 1024; off <<= 1) {
        int v = (t >= off) ? sums[t - off] : 0;
        __syncthreads();
        sums[t] += v;
        __syncthreads();
    }
    int base = (t == 0) ? 0 : sums[t - 1];
    for (int i = start; i < end; ++i) {
        ptr[i] = base; cursor[i] = base;
        base += deg[i] - 1;
    }
}

__global__ void fill_csr(const int* __restrict__ src, const int* __restrict__ dst,
                         int E, int* cursor, int* csr, int n) {
    int e = blockIdx.x * blockDim.x + threadIdx.x;
    if (e < E) {
        int d = dst[e], s = src[e];
        if ((unsigned)d < (unsigned)n && (unsigned)s < (unsigned)n) {
            int pos = atomicAdd(&cursor[d], 1);
            csr[pos] = s;
        }
    }
}

// ---------------- W1 pack: W1[FIN][HID] f32 -> W1s[KT1][1024 segs][8 bf16]
// seg = g*128 + c  (g = k-octet within BK tile, c = output col); LDS-tile order.
__global__ void prep_w1(const float* __restrict__ W1, unsigned short* __restrict__ W1s) {
    int tid = blockIdx.x * 256 + threadIdx.x;
    if (tid >= KT1 * 1024) return;
    int kt = tid >> 10, seg = tid & 1023;
    int c = seg & 127, g = seg >> 7;
    int kb = kt * BK + g * 8;
    unsigned int w[4];
    #pragma unroll
    for (int p = 0; p < 4; ++p) {
        int k0 = kb + p * 2, k1 = kb + p * 2 + 1;
        unsigned short lo = (k0 < FIN) ? f2bf(W1[(size_t)k0 * HID + c]) : (unsigned short)0;
        unsigned short hi = (k1 < FIN) ? f2bf(W1[(size_t)k1 * HID + c]) : (unsigned short)0;
        w[p] = (unsigned int)lo | ((unsigned int)hi << 16);
    }
    uint4* dstp = (uint4*)(W1s + (size_t)tid * 8);
    uint4 val; val.x = w[0]; val.y = w[1]; val.z = w[2]; val.w = w[3];
    *dstp = val;
}

// ---------------- GEMM1: h[M][128] (bf16) = x[M][1433] @ W1 ----------------
// BM=128, BK=64, 512 threads / 8 waves (4 row-groups x 2 col-groups).
// Double-buffered LDS, ONE barrier per K-iter, A reg-staged (issue-early/
// write-late), B via global_load_lds from pre-packed W1s.
__global__ __launch_bounds__(512, 4) void gemm1(const float* __restrict__ x,
                                                const unsigned short* __restrict__ W1s,
                                                unsigned short* __restrict__ h, int M) {
    // A: [row 128][(g*8) ^ ((row&7)<<3) ..+7] ushorts (XOR-swizzled, 16KB/buf)
    // B: [g 8][c 128][8] ushorts (linear, gload_lds order, 16KB/buf)
    __shared__ unsigned short As[2][8192];
    __shared__ unsigned short Bs[2][8192];
    const int t = threadIdx.x;
    const int wave = t >> 6, lane = t & 63;
    const int wm = wave >> 1, wn = wave & 1;
    const int r = lane & 15, u = lane >> 4;
    const int rowBase = blockIdx.x * BM;
    f32x4 acc[2][4] = {};

    float4 areg[4];

    auto issueA = [&](int kt) {
        int k0 = kt * BK;
        #pragma unroll
        for (int i = 0; i < 4; ++i) {
            int quad = i * 512 + t;
            int row = quad >> 4, kq = quad & 15;
            int gr = rowBase + row;
            int gk = k0 + kq * 4;
            if (gr < M && gk + 3 < FIN) {
                f32x4u v = *(const f32x4u*)(x + (size_t)gr * FIN + gk);
                areg[i].x = v.x; areg[i].y = v.y; areg[i].z = v.z; areg[i].w = v.w;
            } else {
                areg[i].x = (gr < M && gk + 0 < FIN) ? x[(size_t)gr * FIN + gk + 0] : 0.f;
                areg[i].y = (gr < M && gk + 1 < FIN) ? x[(size_t)gr * FIN + gk + 1] : 0.f;
                areg[i].z = (gr < M && gk + 2 < FIN) ? x[(size_t)gr * FIN + gk + 2] : 0.f;
                areg[i].w = (gr < M && gk + 3 < FIN) ? x[(size_t)gr * FIN + gk + 3] : 0.f;
            }
        }
    };
    auto issueB = [&](int kt, int buf) {
        #pragma unroll
        for (int i = 0; i < 2; ++i) {
            const unsigned short* gp = W1s + ((size_t)kt * 1024 + (size_t)(i * 512 + t)) * 8;
            unsigned short* lp = &Bs[buf][(i * 512 + wave * 64) * 8];
            __builtin_amdgcn_global_load_lds(
                (const __attribute__((address_space(1))) unsigned int*)gp,
                (__attribute__((address_space(3))) unsigned int*)lp, 16, 0, 0);
        }
    };
    auto writeA = [&](int buf) {
        #pragma unroll
        for (int i = 0; i < 4; ++i) {
            int quad = i * 512 + t;
            int row = quad >> 4, kq = quad & 15;
            unsigned int lo = (unsigned int)f2bf(areg[i].x) | ((unsigned int)f2bf(areg[i].y) << 16);
            unsigned int hi = (unsigned int)f2bf(areg[i].z) | ((unsigned int)f2bf(areg[i].w) << 16);
            unsigned long long pk = ((unsigned long long)hi << 32) | (unsigned long long)lo;
            int us = row * 64 + ((kq * 4) ^ ((row & 7) << 3));
            *(unsigned long long*)(&As[buf][us]) = pk;
        }
    };
    auto compute = [&](int buf) {
        short8_t af[2][2], bfr[2][4];
        #pragma unroll
        for (int ks = 0; ks < 2; ++ks) {
            int g = ks * 4 + u;
            #pragma unroll
            for (int mi = 0; mi < 2; ++mi) {
                int row = wm * 32 + mi * 16 + r;
                int us = row * 64 + ((g * 8) ^ ((row & 7) << 3));
                af[ks][mi] = *(const short8_t*)(&As[buf][us]);
            }
            #pragma unroll
            for (int ni = 0; ni < 4; ++ni) {
                int c = wn * 64 + ni * 16 + r;
                bfr[ks][ni] = *(const short8_t*)(&Bs[buf][g * 1024 + c * 8]);
            }
        }
        #pragma unroll
        for (int ks = 0; ks < 2; ++ks)
            #pragma unroll
            for (int mi = 0; mi < 2; ++mi)
                #pragma unroll
                for (int ni = 0; ni < 4; ++ni)
                    acc[mi][ni] = __builtin_amdgcn_mfma_f32_16x16x32_bf16(af[ks][mi], bfr[ks][ni], acc[mi][ni], 0, 0, 0);
    };

    // prologue: stage tile 0
    issueA(0);
    issueB(0, 0);
    writeA(0);                 // auto vmcnt wait on A loads
    __syncthreads();           // drains B gload_lds + makes A writes visible

    int cur = 0;
    for (int kt = 0; kt < KT1; ++kt) {
        int nxt = cur ^ 1;
        if (kt + 1 < KT1) { issueA(kt + 1); issueB(kt + 1, nxt); }
        compute(cur);
        if (kt + 1 < KT1) writeA(nxt);   // A[nxt] readers retired before previous barrier
        __syncthreads();                 // one barrier/iter: drains vmcnt+lgkm, publishes nxt
        cur = nxt;
    }

    // epilogue: C layout col=lane&15, row=(lane>>4)*4+reg
    #pragma unroll
    for (int mi = 0; mi < 2; ++mi) {
        #pragma unroll
        for (int reg = 0; reg < 4; ++reg) {
            int grow = rowBase + wm * 32 + mi * 16 + u * 4 + reg;
            if (grow < M) {
                #pragma unroll
                for (int ni = 0; ni < 4; ++ni) {
                    int gcol = wn * 64 + ni * 16 + r;
                    h[(size_t)grow * HID + gcol] = f2bf(acc[mi][ni][reg]);
                }
            }
        }
    }
}

// ---------------- Aggregation 1 + bias + relu + @W2 fused ----------------
__global__ __launch_bounds__(256) void agg1(const unsigned short* __restrict__ h,
                                            const int* __restrict__ ptr,
                                            const int* __restrict__ deg,
                                            const int* __restrict__ csr,
                                            const float* __restrict__ dinv,
                                            const float* __restrict__ b1,
                                            const float* __restrict__ W2,
                                            float* __restrict__ h2s, int n) {
    __shared__ float W2s[HID * NCLS];
    for (int i = threadIdx.x; i < HID * NCLS; i += 256) W2s[i] = W2[i];
    __syncthreads();
    int wave = threadIdx.x >> 6, lane = threadIdx.x & 63;
    int v = blockIdx.x * 4 + wave;
    if (v >= n) return;
    float dv = dinv[v];
    int p0 = ptr[v], cnt = deg[v] - 1;
    float a0 = 0.f, a1 = 0.f;
    {
        unsigned int hv = *(const unsigned int*)(h + (size_t)v * HID + lane * 2);
        float nrm = dv * dv;
        a0 += nrm * bf2f((unsigned short)(hv & 0xffffu));
        a1 += nrm * bf2f((unsigned short)(hv >> 16));
    }
    #pragma unroll 4
    for (int j = 0; j < cnt; ++j) {
        int s = csr[p0 + j];
        float nrm = dv * dinv[s];
        unsigned int hv = *(const unsigned int*)(h + (size_t)s * HID + lane * 2);
        a0 += nrm * bf2f((unsigned short)(hv & 0xffffu));
        a1 += nrm * bf2f((unsigned short)(hv >> 16));
    }
    int f0 = lane * 2, f1 = lane * 2 + 1;
    float v0 = fmaxf(a0 + b1[f0], 0.f);
    float v1 = fmaxf(a1 + b1[f1], 0.f);
    float p[NCLS];
    #pragma unroll
    for (int c = 0; c < NCLS; ++c)
        p[c] = v0 * W2s[f0 * NCLS + c] + v1 * W2s[f1 * NCLS + c];
    #pragma unroll
    for (int off = 32; off >= 1; off >>= 1)
        #pragma unroll
        for (int c = 0; c < NCLS; ++c)
            p[c] += __shfl_xor(p[c], off, 64);
    if (lane == 0) {
        #pragma unroll
        for (int c = 0; c < NCLS; ++c) h2s[(size_t)v * 8 + c] = p[c];
        h2s[(size_t)v * 8 + 7] = 0.f;
    }
}

// ---------------- Aggregation 2 + bias ----------------
__global__ __launch_bounds__(256) void agg2(const float* __restrict__ h2s,
                                            const int* __restrict__ ptr,
                                            const int* __restrict__ deg,
                                            const int* __restrict__ csr,
                                            const float* __restrict__ dinv,
                                            const float* __restrict__ b2,
                                            float* __restrict__ out, int n) {
    int g = threadIdx.x >> 3, c = threadIdx.x & 7;
    int v = blockIdx.x * 32 + g;
    if (v >= n) return;
    float dv = dinv[v];
    int p0 = ptr[v], cnt = deg[v] - 1;
    float acc = dv * dv * h2s[(size_t)v * 8 + c];
    #pragma unroll 4
    for (int j = 0; j < cnt; ++j) {
        int s = csr[p0 + j];
        acc += dv * dinv[s] * h2s[(size_t)s * 8 + c];
    }
    if (c < NCLS) out[(size_t)v * NCLS + c] = acc + b2[c];
}

extern "C" void kernel_launch(void* const* d_in, const int* in_sizes, int n_in,
                              void* d_out, int out_size, void* d_ws, size_t ws_size,
                              hipStream_t stream) {
    const float* x  = (const float*)d_in[0];
    const int*   ei = (const int*)d_in[1];    // int64 in reference but JAX x64-off => int32
    const float* W1 = (const float*)d_in[2];
    const float* b1 = (const float*)d_in[3];
    const float* W2 = (const float*)d_in[4];
    const float* b2 = (const float*)d_in[5];
    float* out = (float*)d_out;

    const int N = NNODES;
    const int E = in_sizes[1] / 2;
    const int* src = ei;
    const int* dst = ei + E;

    char* ws = (char*)d_ws;
    size_t off = 0;
    auto alloc = [&](size_t bytes) {
        void* p = ws + off;
        off += (bytes + 255) & ~(size_t)255;
        return p;
    };
    int*   deg    = (int*)alloc((size_t)N * 4);
    float* dinv   = (float*)alloc((size_t)N * 4);
    int*   ptr    = (int*)alloc((size_t)N * 4);
    int*   cursor = (int*)alloc((size_t)N * 4);
    int*   csr    = (int*)alloc((size_t)E * 4);
    unsigned short* W1s = (unsigned short*)alloc((size_t)KT1 * 1024 * 8 * 2);
    unsigned short* h   = (unsigned short*)alloc((size_t)N * HID * 2);
    float* h2s    = (float*)alloc((size_t)N * 8 * 4);

    init_deg<<<(N + 255) / 256, 256, 0, stream>>>(deg, N);
    count_deg<<<(E + 255) / 256, 256, 0, stream>>>(dst, E, deg, N);
    calc_dinv<<<(N + 255) / 256, 256, 0, stream>>>(deg, dinv, N);
    scan_deg<<<1, 1024, 0, stream>>>(deg, ptr, cursor, N);
    fill_csr<<<(E + 255) / 256, 256, 0, stream>>>(src, dst, E, cursor, csr, N);
    prep_w1<<<(KT1 * 1024 + 255) / 256, 256, 0, stream>>>(W1, W1s);
    gemm1<<<(N + BM - 1) / BM, 512, 0, stream>>>(x, W1s, h, N);
    agg1<<<(N + 3) / 4, 256, 0, stream>>>(h, ptr, deg, csr, dinv, b1, W2, h2s, N);
    agg2<<<(N + 31) / 32, 256, 0, stream>>>(h2s, ptr, deg, csr, dinv, b2, out, N);
}